// Round 1
// baseline (39.108 us; speedup 1.0000x reference)
//
#include <hip/hip_runtime.h>

#define NEXP 16
#define FIN 256
#define FOUT 256
#define NB 16
#define NPG 128
#define NTOT (NB * NPG)

// ---------------------------------------------------------------------------
// Kernel 1: mixed[b][i][o] = sum_e coeffs[b][e] * kernel[e][i][o]
// One thread per float4 of the (IN x OUT) matrix; reads kernel exactly once.
// grid = (FIN*FOUT/4)/256 = 64 blocks, 256 threads.
// ---------------------------------------------------------------------------
__global__ __launch_bounds__(256) void mole_mix_kernel(
    const float* __restrict__ kern,    // (E, IN, OUT)
    const float* __restrict__ coeffs,  // (B, E)
    float* __restrict__ mixed)         // (B, IN, OUT)
{
    const int t = blockIdx.x * 256 + threadIdx.x;  // float4 index in IN*OUT/4

    __shared__ float cs[NB * NEXP];  // 256 floats
    cs[threadIdx.x] = coeffs[threadIdx.x];
    __syncthreads();

    const float4* k4 = reinterpret_cast<const float4*>(kern);
    float4* m4 = reinterpret_cast<float4*>(mixed);
    const int mat4 = FIN * FOUT / 4;  // 16384

    float4 k[NEXP];
#pragma unroll
    for (int e = 0; e < NEXP; ++e) k[e] = k4[e * mat4 + t];

#pragma unroll
    for (int b = 0; b < NB; ++b) {
        float4 acc = make_float4(0.f, 0.f, 0.f, 0.f);
#pragma unroll
        for (int e = 0; e < NEXP; ++e) {
            const float c = cs[b * NEXP + e];
            acc.x += c * k[e].x;
            acc.y += c * k[e].y;
            acc.z += c * k[e].z;
            acc.w += c * k[e].w;
        }
        m4[b * mat4 + t] = acc;
    }
}

// ---------------------------------------------------------------------------
// Kernel 2: out[n][o] = sum_i in[n][i] * mixed[g(n)][i][o] + bias[o]
// Block tile: 8 nodes x 256 cols. grid = NTOT/8 = 256 blocks, 256 threads.
// Thread t: o4 = t & 63 (float4 column), half = t >> 6; handles local nodes
// {half, half+4}. Input rows staged in LDS (broadcast reads).
// ---------------------------------------------------------------------------
__global__ __launch_bounds__(256) void mole_gemm_kernel(
    const float* __restrict__ inp,     // (N, IN)
    const int* __restrict__ n_node,    // (B,)
    const float* __restrict__ mixed,   // (B, IN, OUT)
    const float* __restrict__ bias,    // (OUT,)
    float* __restrict__ out)           // (N, OUT)
{
    const int n0 = blockIdx.x * 8;  // first node of this block

    __shared__ float in_s[8][FIN];   // 8 KB
    __shared__ int gm[8];            // graph id per local node

    // graph id per local node via prefix scan of n_node (general / ragged-safe)
    if (threadIdx.x < 8) {
        const int n = n0 + threadIdx.x;
        int g = 0, acc = 0;
        for (int b = 0; b < NB; ++b) {
            acc += n_node[b];
            if (n >= acc) ++g;
        }
        gm[threadIdx.x] = g;
    }

    // stage 8 input rows (contiguous 8 KB) as float4
    {
        const float4* ip4 = reinterpret_cast<const float4*>(inp + (size_t)n0 * FIN);
        float4* s4 = reinterpret_cast<float4*>(&in_s[0][0]);
        s4[threadIdx.x] = ip4[threadIdx.x];
        s4[threadIdx.x + 256] = ip4[threadIdx.x + 256];
    }
    __syncthreads();

    const int o4 = threadIdx.x & 63;
    const int half = threadIdx.x >> 6;

    const int mat4 = FIN * FOUT / 4;  // 16384 float4 per graph matrix
    const float4* m0 = reinterpret_cast<const float4*>(mixed) + (size_t)gm[half] * mat4 + o4;
    const float4* m1 = reinterpret_cast<const float4*>(mixed) + (size_t)gm[half + 4] * mat4 + o4;

    float4 acc0 = make_float4(0.f, 0.f, 0.f, 0.f);
    float4 acc1 = make_float4(0.f, 0.f, 0.f, 0.f);

#pragma unroll 8
    for (int i = 0; i < FIN; ++i) {
        const float a0 = in_s[half][i];
        const float a1 = in_s[half + 4][i];
        const float4 mv0 = m0[i * (FOUT / 4)];
        const float4 mv1 = m1[i * (FOUT / 4)];
        acc0.x += a0 * mv0.x;
        acc0.y += a0 * mv0.y;
        acc0.z += a0 * mv0.z;
        acc0.w += a0 * mv0.w;
        acc1.x += a1 * mv1.x;
        acc1.y += a1 * mv1.y;
        acc1.z += a1 * mv1.z;
        acc1.w += a1 * mv1.w;
    }

    const float4 bv = reinterpret_cast<const float4*>(bias)[o4];
    acc0.x += bv.x; acc0.y += bv.y; acc0.z += bv.z; acc0.w += bv.w;
    acc1.x += bv.x; acc1.y += bv.y; acc1.z += bv.z; acc1.w += bv.w;

    float4* out4 = reinterpret_cast<float4*>(out);
    out4[(size_t)(n0 + half) * (FOUT / 4) + o4] = acc0;
    out4[(size_t)(n0 + half + 4) * (FOUT / 4) + o4] = acc1;
}

// ---------------------------------------------------------------------------
extern "C" void kernel_launch(void* const* d_in, const int* in_sizes, int n_in,
                              void* d_out, int out_size, void* d_ws, size_t ws_size,
                              hipStream_t stream) {
    const float* inputs = (const float*)d_in[0];   // (N, IN) f32
    const int* n_node = (const int*)d_in[1];       // (B,) i32
    const float* coeffs = (const float*)d_in[2];   // (B, E) f32
    const float* kern = (const float*)d_in[3];     // (E, IN, OUT) f32
    const float* bias = (const float*)d_in[4];     // (OUT,) f32
    float* out = (float*)d_out;                    // (N, OUT) f32
    float* mixed = (float*)d_ws;                   // (B, IN, OUT) f32 = 4 MB scratch

    mole_mix_kernel<<<(FIN * FOUT / 4) / 256, 256, 0, stream>>>(kern, coeffs, mixed);
    mole_gemm_kernel<<<NTOT / 8, 256, 0, stream>>>(inputs, n_node, mixed, bias, out);
}

// Round 2
// 26.374 us; speedup vs baseline: 1.4828x; 1.4828x over previous
//
#include <hip/hip_runtime.h>

#define NEXP 16
#define FIN 256
#define FOUT 256
#define NB 16
#define NPG 128
#define NTOT (NB * NPG)
#define MAT4 (FIN * FOUT / 4)   // 16384 float4 per (IN,OUT) matrix

// ---------------------------------------------------------------------------
// Kernel 1: mixed[b][i][o] = sum_e coeffs[b][e] * kernel[e][i][o]
// 256 blocks x 256 threads. Block (tb = bid&63, bq = bid>>6): thread owns
// float4 position t = tb*256+tid, covers graphs [4*bq, 4*bq+4).
// kern re-read 4x (16 MB) but L3-resident; 4x the CU parallelism of r0.
// ---------------------------------------------------------------------------
__global__ __launch_bounds__(256) void mole_mix_kernel(
    const float* __restrict__ kern,    // (E, IN, OUT)
    const float* __restrict__ coeffs,  // (B, E)
    float* __restrict__ mixed)         // (B, IN, OUT)
{
    const int tb = blockIdx.x & 63;
    const int bq = blockIdx.x >> 6;                 // graph quarter
    const int t = tb * 256 + threadIdx.x;           // float4 index in matrix

    __shared__ float cs[NB * NEXP];                 // 256 floats
    cs[threadIdx.x] = coeffs[threadIdx.x];
    __syncthreads();

    const float4* k4 = reinterpret_cast<const float4*>(kern);
    float4* m4 = reinterpret_cast<float4*>(mixed);

    float4 k[NEXP];
#pragma unroll
    for (int e = 0; e < NEXP; ++e) k[e] = k4[e * MAT4 + t];

#pragma unroll
    for (int bb = 0; bb < 4; ++bb) {
        const int b = 4 * bq + bb;
        float4 acc = make_float4(0.f, 0.f, 0.f, 0.f);
#pragma unroll
        for (int e = 0; e < NEXP; ++e) {
            const float c = cs[b * NEXP + e];
            acc.x += c * k[e].x;
            acc.y += c * k[e].y;
            acc.z += c * k[e].z;
            acc.w += c * k[e].w;
        }
        m4[(size_t)b * MAT4 + t] = acc;
    }
}

// ---------------------------------------------------------------------------
// Kernel 2: out[n][o] = sum_i in[n][i] * mixed[g(n)][i][o] + bias[o]
// Block tile: 8 nodes x 256 cols, 256 threads, grid = 256.
// Split-K within block: wave q (= tid>>6) handles i in [64q, 64q+64) for ALL
// 8 nodes (acc[8] float4) -> matrix read EXACTLY once per block (256 KB).
// Cross-wave reduction through 32 KB LDS, bias added there.
// ---------------------------------------------------------------------------
__global__ __launch_bounds__(256) void mole_gemm_kernel(
    const float* __restrict__ inp,     // (N, IN)
    const int* __restrict__ n_node,    // (B,)
    const float* __restrict__ mixed,   // (B, IN, OUT)
    const float* __restrict__ bias,    // (OUT,)
    float* __restrict__ out)           // (N, OUT)
{
    const int n0 = blockIdx.x * 8;  // first node of this block

    __shared__ float in_s[8][FIN];        // 8 KB input rows
    __shared__ float4 red_s[4][8][64];    // 32 KB cross-wave partials
    __shared__ int gm[8];                 // graph id per local node

    // graph id per local node via prefix scan of n_node (ragged-safe)
    if (threadIdx.x < 8) {
        const int n = n0 + threadIdx.x;
        int g = 0, acc = 0;
        for (int b = 0; b < NB; ++b) {
            acc += n_node[b];
            if (n >= acc) ++g;
        }
        gm[threadIdx.x] = g;
    }

    // stage 8 input rows (contiguous 8 KB) as float4
    {
        const float4* ip4 = reinterpret_cast<const float4*>(inp + (size_t)n0 * FIN);
        float4* s4 = reinterpret_cast<float4*>(&in_s[0][0]);
        s4[threadIdx.x] = ip4[threadIdx.x];
        s4[threadIdx.x + 256] = ip4[threadIdx.x + 256];
    }
    __syncthreads();

    const int o4 = threadIdx.x & 63;   // float4 column, lanes 0..63 contiguous
    const int q = threadIdx.x >> 6;    // wave id = K-split group
    const int i0 = q * 64;             // this wave's i-range start

    float4 acc[8];
#pragma unroll
    for (int r = 0; r < 8; ++r) acc[r] = make_float4(0.f, 0.f, 0.f, 0.f);

    // gm is monotone nondecreasing -> gm[0]==gm[7] means block is graph-uniform
    if (gm[0] == gm[7]) {
        const float4* mb = reinterpret_cast<const float4*>(mixed)
                         + (size_t)gm[0] * MAT4 + o4;
#pragma unroll 4
        for (int i4 = 0; i4 < 16; ++i4) {
            const int ib = i0 + i4 * 4;
            float4 a[8];
#pragma unroll
            for (int r = 0; r < 8; ++r)
                a[r] = *reinterpret_cast<const float4*>(&in_s[r][ib]);  // wave-broadcast
#pragma unroll
            for (int s = 0; s < 4; ++s) {
                const float4 mv = mb[(size_t)(ib + s) * (FOUT / 4)];
#pragma unroll
                for (int r = 0; r < 8; ++r) {
                    const float av = (s == 0) ? a[r].x : (s == 1) ? a[r].y
                                   : (s == 2) ? a[r].z : a[r].w;
                    acc[r].x += av * mv.x;
                    acc[r].y += av * mv.y;
                    acc[r].z += av * mv.z;
                    acc[r].w += av * mv.w;
                }
            }
        }
    } else {
        // ragged fallback: per-node matrix stream
        const float4* m4 = reinterpret_cast<const float4*>(mixed);
        for (int i = i0; i < i0 + 64; ++i) {
#pragma unroll
            for (int r = 0; r < 8; ++r) {
                const float av = in_s[r][i];
                const float4 mv = m4[(size_t)gm[r] * MAT4 + (size_t)i * (FOUT / 4) + o4];
                acc[r].x += av * mv.x;
                acc[r].y += av * mv.y;
                acc[r].z += av * mv.z;
                acc[r].w += av * mv.w;
            }
        }
    }

    // cross-wave reduction: partials -> LDS
#pragma unroll
    for (int r = 0; r < 8; ++r) red_s[q][r][o4] = acc[r];
    __syncthreads();

    // each thread finalizes 2 (row, col4) outputs: rows q and q+4 at col o4
    const float4 bv = reinterpret_cast<const float4*>(bias)[o4];
    float4* out4 = reinterpret_cast<float4*>(out);
#pragma unroll
    for (int k = 0; k < 2; ++k) {
        const int r = q + 4 * k;
        float4 t = red_s[0][r][o4];
        const float4 t1 = red_s[1][r][o4];
        const float4 t2 = red_s[2][r][o4];
        const float4 t3 = red_s[3][r][o4];
        t.x += t1.x + t2.x + t3.x + bv.x;
        t.y += t1.y + t2.y + t3.y + bv.y;
        t.z += t1.z + t2.z + t3.z + bv.z;
        t.w += t1.w + t2.w + t3.w + bv.w;
        out4[(size_t)(n0 + r) * (FOUT / 4) + o4] = t;
    }
}

// ---------------------------------------------------------------------------
extern "C" void kernel_launch(void* const* d_in, const int* in_sizes, int n_in,
                              void* d_out, int out_size, void* d_ws, size_t ws_size,
                              hipStream_t stream) {
    const float* inputs = (const float*)d_in[0];   // (N, IN) f32
    const int* n_node = (const int*)d_in[1];       // (B,) i32
    const float* coeffs = (const float*)d_in[2];   // (B, E) f32
    const float* kern = (const float*)d_in[3];     // (E, IN, OUT) f32
    const float* bias = (const float*)d_in[4];     // (OUT,) f32
    float* out = (float*)d_out;                    // (N, OUT) f32
    float* mixed = (float*)d_ws;                   // (B, IN, OUT) f32 = 4 MB scratch

    mole_mix_kernel<<<256, 256, 0, stream>>>(kern, coeffs, mixed);
    mole_gemm_kernel<<<NTOT / 8, 256, 0, stream>>>(inputs, n_node, mixed, bias, out);
}